// Round 14
// baseline (315.147 us; speedup 1.0000x reference)
//
#include <hip/hip_runtime.h>
#include <cmath>

// ---------------------------------------------------------------------------
// Fused 3D SSIM, separable Gaussian 11-tap, VALID. fp32 (2,1,192,192,192).
// z-streaming slab, 512 threads, ONE output column per thread, channel-packed
// v_pk_fma_f32 math, TWO planes per phase, 1 barrier/phase, ZC=7.
// Ladder: r5 205 -> r8 178 (staticW+AB-b128+C2) -> r10 160 (grid 1008)
//         -> r13 146 (tile 16x32: W y-halo 1.625->1.3125).
// Model fix from r13: FETCH follows CACHE-LINE halo, not unique bytes
// (16-wide tiles: +24% FETCH at invariant unique-byte product). HBM at 22%
// of peak -- not binding, so the x-for-y halo trade keeps paying.
//
// Round-14 change (isolated): TILE ASPECT 16x32 -> 8x64 (TWD=8, TH=64).
//   W-phase VALU (largest consumer, ~46%) scales with IHR/TH:
//   42/32=1.3125 -> 74/64=1.156 (-12% W). Items 592 -> only waves 0-1
//   carry the 2-item W load (smaller imbalance bubble). Grid 24x3x2x7 =
//   1008 (same quantization). LDS 53.3 KB (2 blocks/CU kept). Bank
//   patterns re-derived: ABS=9 (rows shift 4 banks, 8-words/bank floor
//   on b128 store+read, same as r13); CSTR=9 (row shift 18, spread).
//   FETCH predicted +20-25% (cache-line halo model) -- acceptable at 22%.
//
// REVERT CUE: WRITE_SIZE ballooning (MBs->GBs) = spill (r6 signature).
// DO NOT: b64-only H reads (r9: slower despite fewer counted conflicts);
//         register-prefetch W inputs (r1: -19%); global_load_lds slab
//         prefetch (r4: -20%); size=12 LDS-DMA (r3: corrupts).
// ---------------------------------------------------------------------------

#define WSZ 11
#define DIN 192
#define DOUTS 182
#define TH 64              // tile height (output rows, y)
#define TWD 8              // tile width  (output cols, x)
#define IHR 74             // input rows per plane tile (TH + 10)
#define ZCHB 28            // base output planes per chunk (last chunk: 24)
#define ZC 7               // z-chunks: 6x28 + 1x24 = 192
#define NTX 24             // x tiles (24*8 = 192)
#define NTY 3              // y tiles (3*64 = 192)
#define NBLK (NTX*NTY*2*ZC)  // 1008  (< 2 x 512 resident slots)
#define ABS 9              // AB slots per row (8 + 1 pad -> rows shift 4 banks)
#define CSTR 9             // C2 row stride in x-entries (row shift 18 words)
#define WITEMS (IHR*4)     // 296 W pair-items per plane
static constexpr double SOUT = 2.0 * 182.0 * 182.0 * 182.0;  // 12,057,136

typedef float v2f __attribute__((ext_vector_type(2)));
typedef float v4f __attribute__((ext_vector_type(4)));

struct G11 { float g[WSZ]; };

__device__ __forceinline__ v2f pkfma(float g, v2f v, v2f a) {
    v2f gg = {g, g};
    return __builtin_elementwise_fma(gg, v, a);
}

__device__ __forceinline__ unsigned int enc_f(float f) {
    unsigned int u = __float_as_uint(f);
    return (u & 0x80000000u) ? ~u : (u | 0x80000000u);
}
__device__ __forceinline__ float dec_f(unsigned int u) {
    return (u & 0x80000000u) ? __uint_as_float(u & 0x7FFFFFFFu) : __uint_as_float(~u);
}

// ---------------------------------------------------------------------------
__global__ void k_init(unsigned int* mm, double* sum) {
    sum[0] = 0.0;
    mm[0] = 0u;           // encoded -inf (max accumulator)
    mm[1] = 0xFFFFFFFFu;  // encoded +inf (min accumulator)
}

// ---------------------------------------------------------------------------
__global__ __launch_bounds__(256) void k_minmax(const float4* __restrict__ img1,
                                                int n4, unsigned int* mm) {
    float mx = -1e30f, mn = 1e30f;
    for (int i = blockIdx.x * blockDim.x + threadIdx.x; i < n4;
         i += gridDim.x * blockDim.x) {
        float4 v = img1[i];
        mx = fmaxf(mx, fmaxf(fmaxf(v.x, v.y), fmaxf(v.z, v.w)));
        mn = fminf(mn, fminf(fminf(v.x, v.y), fminf(v.z, v.w)));
    }
    #pragma unroll
    for (int o = 32; o; o >>= 1) {
        mx = fmaxf(mx, __shfl_down(mx, o));
        mn = fminf(mn, __shfl_down(mn, o));
    }
    __shared__ float smx[4], smn[4];
    int lane = threadIdx.x & 63, wv = threadIdx.x >> 6;
    if (lane == 0) { smx[wv] = mx; smn[wv] = mn; }
    __syncthreads();
    if (threadIdx.x == 0) {
        #pragma unroll
        for (int i = 1; i < 4; i++) { mx = fmaxf(mx, smx[i]); mn = fminf(mn, smn[i]); }
        atomicMax(&mm[0], enc_f(mx));
        atomicMin(&mm[1], enc_f(mn));
    }
}

// ---------------------------------------------------------------------------
// 512 threads, tile 8(x) x 64(y), thread owns ONE output column.
// launch_bounds(512,4): reg cap 128 -> 4 waves/SIMD (2 blocks/CU).
__global__ __launch_bounds__(512, 4) void k_ssim(const float* __restrict__ img1,
                                                 const float* __restrict__ img2,
                                                 const unsigned int* __restrict__ mm,
                                                 double* __restrict__ sum, G11 gw) {
    // AB-fused, slot-permuted: twsAB[buf][pl][h][slot] = {mu1,mu2,E11,E22}
    //   slot = perm(x): even x -> x/2, odd x -> 4 + x/2; stride 9 (42.6 KB)
    // E12 plane-fused:  twsC2[buf][h][x] = {E12_pl0, E12_pl1}.     (10.7 KB)
    __shared__ float twsAB[2][2][IHR][ABS][4];
    __shared__ float twsC2[2][IHR][CSTR][2];
    __shared__ float sred[8];

    int b   = blockIdx.x;
    int twi = b % NTX;
    int thi = (b / NTX) % NTY;
    int rest = b / (NTX * NTY);
    int tc  = rest % ZC;
    int n   = rest / ZC;                 // batch 0..1
    int ow0 = twi * TWD, oh0 = thi * TH, od0 = tc * ZCHB;
    int nph = (tc == ZC - 1) ? 17 : 19;  // (24+10)/2 or (28+10)/2 phases
    int tid = threadIdx.x;
    int y = tid >> 3, x = tid & 7;       // thread owns output (y, x)
    int sx = (x & 1) ? (4 + (x >> 1)) : (x >> 1);   // perm(x), loop-invariant

    // SSIM constants (L from img1 min/max, computed by k_minmax)
    float maxv = dec_f(mm[0]);
    float minv = dec_f(mm[1]);
    float max_val = (maxv > 128.0f) ? 255.0f : 1.0f;
    float min_val = (minv < -0.5f) ? -1.0f : 0.0f;
    float L  = max_val - min_val;
    float C1 = 0.01f * L; C1 *= C1;
    float C2 = 0.03f * L; C2 *= C2;

    bool vout = (oh0 + y < DOUTS) && (ow0 + x < DOUTS);

    // ---- Static W-item geometry (hoisted; each thread has <=2 fixed items).
    // 592 pair-items/phase (2 planes x 296 = 74 rows x 4 x-pairs).
    // item0: tid<296 -> (pl=0, idx=tid); tid>=296 -> (pl=1, idx=tid-296).
    // item1: only tid<80 -> (pl=1, idx=tid+216).
    int pl0  = (tid >= WITEMS) ? 1 : 0;
    int idx0 = tid - (pl0 ? WITEMS : 0);
    int wh0  = idx0 >> 2, sl0 = idx0 & 3, xo0 = 2 * sl0;
    bool has1 = (tid < 2 * WITEMS - 512);          // 80
    int idx1 = tid + (512 - WITEMS);               // tid + 216
    int wh1  = idx1 >> 2, sl1 = idx1 & 3, xo1 = 2 * sl1;
    // Clamped rows/cols feed only masked outputs; loads stay in-bounds.
    unsigned rowoff0 = (unsigned)(min(oh0 + wh0, DIN - 1) * DIN
                                  + min(ow0 + xo0, DIN - 12));
    unsigned rowoff1 = (unsigned)(min(oh0 + wh1, DIN - 1) * DIN
                                  + min(ow0 + xo1, DIN - 12));
    const float* i1 = img1 + (size_t)n * DIN * DIN * DIN;   // SGPR base
    const float* i2 = img2 + (size_t)n * DIN * DIN * DIN;

// One W pair-item: x-conv of 12 input floats -> 2 outputs x 5 channels.
// Lane-pair of every v2f is (img1, img2). Stores: 2x b128 at 16 B lane-stride,
// rows shift 4 banks (ABS=9) -> 8-words/bank floor; 2x b32.
#define WCONV_ITEM(PL, WH, SL, XO, OFF)                                       \
    {                                                                         \
        const float2* p1 = (const float2*)(i1 + (OFF));                       \
        const float2* p2 = (const float2*)(i2 + (OFF));                       \
        v2f p[12];                                                            \
        _Pragma("unroll")                                                     \
        for (int q = 0; q < 6; q++) {                                         \
            float2 f1 = p1[q]; float2 f2 = p2[q];                             \
            p[2*q]   = (v2f){f1.x, f2.x};                                     \
            p[2*q+1] = (v2f){f1.y, f2.y};                                     \
        }                                                                     \
        v2f amu0 = {0.f,0.f}, amu1 = {0.f,0.f};                               \
        v2f asq0 = {0.f,0.f}, asq1 = {0.f,0.f};                               \
        float a120 = 0.f, a121 = 0.f;                                         \
        _Pragma("unroll")                                                     \
        for (int k = 0; k < WSZ; k++) {                                       \
            float g = gw.g[k];                                                \
            v2f e0 = p[k], e1 = p[k + 1];                                     \
            v2f t0 = (v2f){g, g} * e0, t1 = (v2f){g, g} * e1;                 \
            amu0 += t0; amu1 += t1;                                           \
            asq0 = __builtin_elementwise_fma(t0, e0, asq0);                   \
            asq1 = __builtin_elementwise_fma(t1, e1, asq1);                   \
            a120 = fmaf(t0.x, e0.y, a120);                                    \
            a121 = fmaf(t1.x, e1.y, a121);                                    \
        }                                                                     \
        *(v4f*)&twsAB[buf][PL][WH][SL][0]     = (v4f){amu0.x, amu0.y,         \
                                                      asq0.x, asq0.y};        \
        *(v4f*)&twsAB[buf][PL][WH][SL + 4][0] = (v4f){amu1.x, amu1.y,         \
                                                      asq1.x, asq1.y};        \
        twsC2[buf][WH][XO][PL]     = a120;                                    \
        twsC2[buf][WH][XO + 1][PL] = a121;                                    \
    }

    // D-conv packed shift pipeline: index j covers output zo = zi - j.
    v2f accMu[WSZ], accE[WSZ];
    float acc12[WSZ];
    float local = 0.f;

    for (int t = 0; t < nph; t++) {
        int buf = t & 1;
        int zb  = od0 + 2 * t;

        // ---- W phase: 592 pair-items as 2 static items/thread ----
        {
            int d0 = min(zb + pl0, DIN - 1);     // clamped planes -> masked zo
            unsigned off0 = (unsigned)(d0 * (DIN * DIN)) + rowoff0;
            WCONV_ITEM(pl0, wh0, sl0, xo0, off0);
        }
        if (has1) {
            int d1 = min(zb + 1, DIN - 1);
            unsigned off1 = (unsigned)(d1 * (DIN * DIN)) + rowoff1;
            WCONV_ITEM(1, wh1, sl1, xo1, off1);
        }
        __syncthreads();   // only barrier per phase (2 planes)

        // ---- H phase: y-conv, 2 b128 + 1 b64 per tap (both planes) ----
        v2f aMu0 = {0.f,0.f}, aE0 = {0.f,0.f};
        v2f aMu1 = {0.f,0.f}, aE1 = {0.f,0.f};
        v2f c12  = {0.f,0.f};
        #pragma unroll
        for (int k = 0; k < WSZ; k++) {
            float g = gw.g[k];
            v4f va = *(const v4f*)&twsAB[buf][0][y + k][sx][0];
            v4f vb = *(const v4f*)&twsAB[buf][1][y + k][sx][0];
            v2f cc = *(const v2f*)&twsC2[buf][y + k][x][0];
            aMu0 = pkfma(g, (v2f){va.x, va.y}, aMu0);
            aE0  = pkfma(g, (v2f){va.z, va.w}, aE0);
            aMu1 = pkfma(g, (v2f){vb.x, vb.y}, aMu1);
            aE1  = pkfma(g, (v2f){vb.z, vb.w}, aE1);
            c12  = pkfma(g, cc, c12);
        }
        v2f mMu[2] = {aMu0, aMu1};
        v2f mE[2]  = {aE0,  aE1};
        float m12[2] = {c12.x, c12.y};
        // No second barrier: W(t+2) reuses this dbuf half only after every
        // wave passes barrier(t+1), which follows every wave's H(t).

        // ---- D shift-FMA + SSIM, once per plane ----
        #pragma unroll
        for (int pl = 0; pl < 2; pl++) {
            #pragma unroll
            for (int j = WSZ - 1; j >= 1; j--) {
                accMu[j] = pkfma(gw.g[j], mMu[pl], accMu[j-1]);
                accE[j]  = pkfma(gw.g[j], mE[pl],  accE[j-1]);
                acc12[j] = fmaf(gw.g[j], m12[pl], acc12[j-1]);
            }
            accMu[0] = (v2f){gw.g[0], gw.g[0]} * mMu[pl];
            accE[0]  = (v2f){gw.g[0], gw.g[0]} * mE[pl];
            acc12[0] = gw.g[0] * m12[pl];

            int zi = 2 * t + pl;
            if (zi >= WSZ - 1) {
                int zo = od0 + zi - (WSZ - 1);
                if (zo < DOUTS && vout) {
                    float mu1 = accMu[10].x, mu2 = accMu[10].y;
                    float mu1s = mu1 * mu1, mu2s = mu2 * mu2, mu12 = mu1 * mu2;
                    float s1  = accE[10].x - mu1s;
                    float s2  = accE[10].y - mu2s;
                    float s12 = acc12[10] - mu12;
                    float v1  = 2.f * s12 + C2;
                    float v2  = s1 + s2 + C2;
                    float num = (2.f * mu12 + C1) * v1;
                    float den = (mu1s + mu2s + C1) * v2;
                    local += num / den;
                }
            }
        }
    }
#undef WCONV_ITEM

    // ---- block reduction (8 waves) -> one f64 atomic ----
    #pragma unroll
    for (int o = 32; o; o >>= 1) local += __shfl_down(local, o);
    if ((tid & 63) == 0) sred[tid >> 6] = local;
    __syncthreads();
    if (tid == 0) {
        float tsum = 0.f;
        #pragma unroll
        for (int i = 0; i < 8; i++) tsum += sred[i];
        atomicAdd(sum, (double)tsum);
    }
}

// ---------------------------------------------------------------------------
__global__ void k_final(const double* __restrict__ sum, float* __restrict__ out) {
    out[0] = (float)(sum[0] / SOUT);
}

// ---------------------------------------------------------------------------
extern "C" void kernel_launch(void* const* d_in, const int* in_sizes, int n_in,
                              void* d_out, int out_size, void* d_ws, size_t ws_size,
                              hipStream_t stream) {
    const float* img1 = (const float*)d_in[0];
    const float* img2 = (const float*)d_in[1];
    float* out = (float*)d_out;

    char* ws = (char*)d_ws;
    double*       sum = (double*)ws;              // 8 B
    unsigned int* mm  = (unsigned int*)(ws + 8);  // 8 B

    // Gaussian weights: f64 compute, normalize, cast to f32 (matches ref).
    G11 g;
    {
        double gd[WSZ], s = 0.0;
        for (int i = 0; i < WSZ; i++) {
            double d = (double)(i - WSZ / 2);
            gd[i] = std::exp(-(d * d) / (2.0 * 1.5 * 1.5));
            s += gd[i];
        }
        for (int i = 0; i < WSZ; i++) g.g[i] = (float)(gd[i] / s);
    }

    int n_img = 2 * DIN * DIN * DIN;  // 14,155,776

    k_init<<<1, 1, 0, stream>>>(mm, sum);
    k_minmax<<<2048, 256, 0, stream>>>((const float4*)img1, n_img / 4, mm);
    k_ssim<<<NBLK, 512, 0, stream>>>(img1, img2, mm, sum, g);
    k_final<<<1, 1, 0, stream>>>(sum, out);
}

// Round 15
// 262.846 us; speedup vs baseline: 1.1990x; 1.1990x over previous
//
#include <hip/hip_runtime.h>
#include <cmath>

// ---------------------------------------------------------------------------
// Fused 3D SSIM, separable Gaussian 11-tap, VALID. fp32 (2,1,192,192,192).
// z-streaming slab, 512 threads, ONE output column per thread, channel-packed
// v_pk_fma_f32 math, TWO planes per phase, 1 barrier/phase, ZC=7.
// Ladder: r5 205 -> r8 178 -> r10 160 (grid 1008) -> r13 146 (tile 16x32).
// r14 (8x64) REGRESSED (173us: cache-line halo +60% FETCH, conflicts x2.6)
// -> tile aspect is bitonic, 16x32 is the optimum. k_ssim body here is
// byte-identical to r13.
//
// Round-15 change (auxiliary pipeline only): total dur exceeds k_ssim by a
// CONSTANT ~135-140us every round (r5:342-205, r8:313-178, r13:288-147).
// Suspect: k_minmax's 2048 blocks x 2 same-address atomicMax/Min = 4096
// serialized L2 atomics (~100us), plus two 1-thread kernel launches.
//   1. k_minmax: 512 blocks, NO atomics -- per-block min/max to plain float
//      arrays in ws (disjoint stores).
//   2. Final 512-value reduction folded into k_ssim entry (shfl+LDS reduce,
//      ~20 instrs + 1 barrier, amortized over 19 phases; stream ordering
//      guarantees k_minmax completed).
//   3. k_init replaced by hipMemsetAsync(sum, 0, 8) (memset node << kernel
//      node; harness itself uses memsetAsync under graph capture).
// HYPOTHESIS TEST: dur 288 -> ~175-195 if atomic-serialization is the cost;
// if only ~265-280, overhead is fixed graph latency -> structural floor.
//
// REVERT CUE: WRITE_SIZE ballooning (MBs->GBs) = spill (r6 signature).
// DO NOT: 8-wide tiles (r14: +60% FETCH); b64-only H reads (r9);
//         register-prefetch W inputs (r1); global_load_lds slab prefetch
//         (r4); size=12 LDS-DMA (r3: corrupts).
// ---------------------------------------------------------------------------

#define WSZ 11
#define DIN 192
#define DOUTS 182
#define TH 32              // tile height (output rows, y)
#define TWD 16             // tile width  (output cols, x)
#define IHR 42             // input rows per plane tile (TH + 10)
#define ZCHB 28            // base output planes per chunk (last chunk: 24)
#define ZC 7               // z-chunks: 6x28 + 1x24 = 192
#define NTX 12             // x tiles (12*16 = 192)
#define NTY 6              // y tiles (6*32 = 192)
#define NBLK (NTX*NTY*2*ZC)  // 1008  (< 2 x 512 resident slots)
#define ABS 17             // AB slots per row (16 + 1 pad -> rows shift 4 banks)
#define CSTR 17            // C2 row stride in x-entries
#define WITEMS (IHR*8)     // 336 W pair-items per plane
#define MMB 512            // k_minmax blocks (per-block partials, no atomics)
static constexpr double SOUT = 2.0 * 182.0 * 182.0 * 182.0;  // 12,057,136

typedef float v2f __attribute__((ext_vector_type(2)));
typedef float v4f __attribute__((ext_vector_type(4)));

struct G11 { float g[WSZ]; };

__device__ __forceinline__ v2f pkfma(float g, v2f v, v2f a) {
    v2f gg = {g, g};
    return __builtin_elementwise_fma(gg, v, a);
}

// ---------------------------------------------------------------------------
// Per-block min/max partials of img1; NO atomics (512 disjoint stores).
__global__ __launch_bounds__(256) void k_minmax(const float4* __restrict__ img1,
                                                int n4, float* __restrict__ pbmx,
                                                float* __restrict__ pbmn) {
    float mx = -1e30f, mn = 1e30f;
    for (int i = blockIdx.x * blockDim.x + threadIdx.x; i < n4;
         i += MMB * 256) {
        float4 v = img1[i];
        mx = fmaxf(mx, fmaxf(fmaxf(v.x, v.y), fmaxf(v.z, v.w)));
        mn = fminf(mn, fminf(fminf(v.x, v.y), fminf(v.z, v.w)));
    }
    #pragma unroll
    for (int o = 32; o; o >>= 1) {
        mx = fmaxf(mx, __shfl_down(mx, o));
        mn = fminf(mn, __shfl_down(mn, o));
    }
    __shared__ float smx[4], smn[4];
    int lane = threadIdx.x & 63, wv = threadIdx.x >> 6;
    if (lane == 0) { smx[wv] = mx; smn[wv] = mn; }
    __syncthreads();
    if (threadIdx.x == 0) {
        #pragma unroll
        for (int i = 1; i < 4; i++) { mx = fmaxf(mx, smx[i]); mn = fminf(mn, smn[i]); }
        pbmx[blockIdx.x] = mx;
        pbmn[blockIdx.x] = mn;
    }
}

// ---------------------------------------------------------------------------
// 512 threads, tile 16(x) x 32(y), thread owns ONE output column.
// launch_bounds(512,4): reg cap 128 -> 4 waves/SIMD (2 blocks/CU).
__global__ __launch_bounds__(512, 4) void k_ssim(const float* __restrict__ img1,
                                                 const float* __restrict__ img2,
                                                 const float* __restrict__ pbmx,
                                                 const float* __restrict__ pbmn,
                                                 double* __restrict__ sum, G11 gw) {
    // AB-fused, slot-permuted: twsAB[buf][pl][h][slot] = {mu1,mu2,E11,E22}
    //   slot = perm(x): even x -> x/2, odd x -> 8 + x/2; stride 17 (44.6 KB)
    // E12 plane-fused:  twsC2[buf][h][x] = {E12_pl0, E12_pl1}.     (11.2 KB)
    __shared__ float twsAB[2][2][IHR][ABS][4];
    __shared__ float twsC2[2][IHR][CSTR][2];
    __shared__ float sred[8];
    __shared__ float smx[8], smn[8];

    int b   = blockIdx.x;
    int twi = b % NTX;
    int thi = (b / NTX) % NTY;
    int rest = b / (NTX * NTY);
    int tc  = rest % ZC;
    int n   = rest / ZC;                 // batch 0..1
    int ow0 = twi * TWD, oh0 = thi * TH, od0 = tc * ZCHB;
    int nph = (tc == ZC - 1) ? 17 : 19;  // (24+10)/2 or (28+10)/2 phases
    int tid = threadIdx.x;
    int y = tid >> 4, x = tid & 15;      // thread owns output (y, x)
    int sx = (x & 1) ? (8 + (x >> 1)) : (x >> 1);   // perm(x), loop-invariant

    // ---- entry reduction: fold the 512 per-block minmax partials ----
    {
        float bmx = pbmx[tid];           // MMB == blockDim: one partial/thread
        float bmn = pbmn[tid];
        #pragma unroll
        for (int o = 32; o; o >>= 1) {
            bmx = fmaxf(bmx, __shfl_down(bmx, o));
            bmn = fminf(bmn, __shfl_down(bmn, o));
        }
        if ((tid & 63) == 0) { smx[tid >> 6] = bmx; smn[tid >> 6] = bmn; }
    }
    __syncthreads();
    float maxv = smx[0], minv = smn[0];
    #pragma unroll
    for (int i = 1; i < 8; i++) {
        maxv = fmaxf(maxv, smx[i]);
        minv = fminf(minv, smn[i]);
    }

    // SSIM constants (L from img1 min/max)
    float max_val = (maxv > 128.0f) ? 255.0f : 1.0f;
    float min_val = (minv < -0.5f) ? -1.0f : 0.0f;
    float L  = max_val - min_val;
    float C1 = 0.01f * L; C1 *= C1;
    float C2 = 0.03f * L; C2 *= C2;

    bool vout = (oh0 + y < DOUTS) && (ow0 + x < DOUTS);

    // ---- Static W-item geometry (hoisted; each thread has <=2 fixed items).
    // 672 pair-items/phase (2 planes x 336 = 42 rows x 8 x-pairs).
    // item0: tid<336 -> (pl=0, idx=tid); tid>=336 -> (pl=1, idx=tid-336).
    // item1: only tid<160 -> (pl=1, idx=tid+176).
    int pl0  = (tid >= WITEMS) ? 1 : 0;
    int idx0 = tid - (pl0 ? WITEMS : 0);
    int wh0  = idx0 >> 3, sl0 = idx0 & 7, xo0 = 2 * sl0;
    bool has1 = (tid < 2 * WITEMS - 512);          // 160
    int idx1 = tid + 176;
    int wh1  = idx1 >> 3, sl1 = idx1 & 7, xo1 = 2 * sl1;
    // Clamped rows/cols feed only masked outputs; loads stay in-bounds.
    unsigned rowoff0 = (unsigned)(min(oh0 + wh0, DIN - 1) * DIN
                                  + min(ow0 + xo0, DIN - 12));
    unsigned rowoff1 = (unsigned)(min(oh0 + wh1, DIN - 1) * DIN
                                  + min(ow0 + xo1, DIN - 12));
    const float* i1 = img1 + (size_t)n * DIN * DIN * DIN;   // SGPR base
    const float* i2 = img2 + (size_t)n * DIN * DIN * DIN;

// One W pair-item: x-conv of 12 input floats -> 2 outputs x 5 channels.
// Lane-pair of every v2f is (img1, img2). Stores: 2x b128 at 16 B lane-stride,
// rows shift 4 banks (ABS=17) -> 8-words/bank floor; 2x b32.
#define WCONV_ITEM(PL, WH, SL, XO, OFF)                                       \
    {                                                                         \
        const float2* p1 = (const float2*)(i1 + (OFF));                       \
        const float2* p2 = (const float2*)(i2 + (OFF));                       \
        v2f p[12];                                                            \
        _Pragma("unroll")                                                     \
        for (int q = 0; q < 6; q++) {                                         \
            float2 f1 = p1[q]; float2 f2 = p2[q];                             \
            p[2*q]   = (v2f){f1.x, f2.x};                                     \
            p[2*q+1] = (v2f){f1.y, f2.y};                                     \
        }                                                                     \
        v2f amu0 = {0.f,0.f}, amu1 = {0.f,0.f};                               \
        v2f asq0 = {0.f,0.f}, asq1 = {0.f,0.f};                               \
        float a120 = 0.f, a121 = 0.f;                                         \
        _Pragma("unroll")                                                     \
        for (int k = 0; k < WSZ; k++) {                                       \
            float g = gw.g[k];                                                \
            v2f e0 = p[k], e1 = p[k + 1];                                     \
            v2f t0 = (v2f){g, g} * e0, t1 = (v2f){g, g} * e1;                 \
            amu0 += t0; amu1 += t1;                                           \
            asq0 = __builtin_elementwise_fma(t0, e0, asq0);                   \
            asq1 = __builtin_elementwise_fma(t1, e1, asq1);                   \
            a120 = fmaf(t0.x, e0.y, a120);                                    \
            a121 = fmaf(t1.x, e1.y, a121);                                    \
        }                                                                     \
        *(v4f*)&twsAB[buf][PL][WH][SL][0]     = (v4f){amu0.x, amu0.y,         \
                                                      asq0.x, asq0.y};        \
        *(v4f*)&twsAB[buf][PL][WH][SL + 8][0] = (v4f){amu1.x, amu1.y,         \
                                                      asq1.x, asq1.y};        \
        twsC2[buf][WH][XO][PL]     = a120;                                    \
        twsC2[buf][WH][XO + 1][PL] = a121;                                    \
    }

    // D-conv packed shift pipeline: index j covers output zo = zi - j.
    v2f accMu[WSZ], accE[WSZ];
    float acc12[WSZ];
    float local = 0.f;

    for (int t = 0; t < nph; t++) {
        int buf = t & 1;
        int zb  = od0 + 2 * t;

        // ---- W phase: 672 pair-items as 2 static items/thread ----
        {
            int d0 = min(zb + pl0, DIN - 1);     // clamped planes -> masked zo
            unsigned off0 = (unsigned)(d0 * (DIN * DIN)) + rowoff0;
            WCONV_ITEM(pl0, wh0, sl0, xo0, off0);
        }
        if (has1) {
            int d1 = min(zb + 1, DIN - 1);
            unsigned off1 = (unsigned)(d1 * (DIN * DIN)) + rowoff1;
            WCONV_ITEM(1, wh1, sl1, xo1, off1);
        }
        __syncthreads();   // only barrier per phase (2 planes)

        // ---- H phase: y-conv, 2 b128 + 1 b64 per tap (both planes) ----
        v2f aMu0 = {0.f,0.f}, aE0 = {0.f,0.f};
        v2f aMu1 = {0.f,0.f}, aE1 = {0.f,0.f};
        v2f c12  = {0.f,0.f};
        #pragma unroll
        for (int k = 0; k < WSZ; k++) {
            float g = gw.g[k];
            v4f va = *(const v4f*)&twsAB[buf][0][y + k][sx][0];
            v4f vb = *(const v4f*)&twsAB[buf][1][y + k][sx][0];
            v2f cc = *(const v2f*)&twsC2[buf][y + k][x][0];
            aMu0 = pkfma(g, (v2f){va.x, va.y}, aMu0);
            aE0  = pkfma(g, (v2f){va.z, va.w}, aE0);
            aMu1 = pkfma(g, (v2f){vb.x, vb.y}, aMu1);
            aE1  = pkfma(g, (v2f){vb.z, vb.w}, aE1);
            c12  = pkfma(g, cc, c12);
        }
        v2f mMu[2] = {aMu0, aMu1};
        v2f mE[2]  = {aE0,  aE1};
        float m12[2] = {c12.x, c12.y};
        // No second barrier: W(t+2) reuses this dbuf half only after every
        // wave passes barrier(t+1), which follows every wave's H(t).

        // ---- D shift-FMA + SSIM, once per plane ----
        #pragma unroll
        for (int pl = 0; pl < 2; pl++) {
            #pragma unroll
            for (int j = WSZ - 1; j >= 1; j--) {
                accMu[j] = pkfma(gw.g[j], mMu[pl], accMu[j-1]);
                accE[j]  = pkfma(gw.g[j], mE[pl],  accE[j-1]);
                acc12[j] = fmaf(gw.g[j], m12[pl], acc12[j-1]);
            }
            accMu[0] = (v2f){gw.g[0], gw.g[0]} * mMu[pl];
            accE[0]  = (v2f){gw.g[0], gw.g[0]} * mE[pl];
            acc12[0] = gw.g[0] * m12[pl];

            int zi = 2 * t + pl;
            if (zi >= WSZ - 1) {
                int zo = od0 + zi - (WSZ - 1);
                if (zo < DOUTS && vout) {
                    float mu1 = accMu[10].x, mu2 = accMu[10].y;
                    float mu1s = mu1 * mu1, mu2s = mu2 * mu2, mu12 = mu1 * mu2;
                    float s1  = accE[10].x - mu1s;
                    float s2  = accE[10].y - mu2s;
                    float s12 = acc12[10] - mu12;
                    float v1  = 2.f * s12 + C2;
                    float v2  = s1 + s2 + C2;
                    float num = (2.f * mu12 + C1) * v1;
                    float den = (mu1s + mu2s + C1) * v2;
                    local += num / den;
                }
            }
        }
    }
#undef WCONV_ITEM

    // ---- block reduction (8 waves) -> one f64 atomic ----
    #pragma unroll
    for (int o = 32; o; o >>= 1) local += __shfl_down(local, o);
    if ((tid & 63) == 0) sred[tid >> 6] = local;
    __syncthreads();
    if (tid == 0) {
        float tsum = 0.f;
        #pragma unroll
        for (int i = 0; i < 8; i++) tsum += sred[i];
        atomicAdd(sum, (double)tsum);
    }
}

// ---------------------------------------------------------------------------
__global__ void k_final(const double* __restrict__ sum, float* __restrict__ out) {
    out[0] = (float)(sum[0] / SOUT);
}

// ---------------------------------------------------------------------------
extern "C" void kernel_launch(void* const* d_in, const int* in_sizes, int n_in,
                              void* d_out, int out_size, void* d_ws, size_t ws_size,
                              hipStream_t stream) {
    const float* img1 = (const float*)d_in[0];
    const float* img2 = (const float*)d_in[1];
    float* out = (float*)d_out;

    char* ws = (char*)d_ws;
    double* sum  = (double*)ws;                    // 8 B
    float*  pbmx = (float*)(ws + 8);               // 512 floats (2 KB)
    float*  pbmn = (float*)(ws + 8 + MMB * 4);     // 512 floats (2 KB)

    // Gaussian weights: f64 compute, normalize, cast to f32 (matches ref).
    G11 g;
    {
        double gd[WSZ], s = 0.0;
        for (int i = 0; i < WSZ; i++) {
            double d = (double)(i - WSZ / 2);
            gd[i] = std::exp(-(d * d) / (2.0 * 1.5 * 1.5));
            s += gd[i];
        }
        for (int i = 0; i < WSZ; i++) g.g[i] = (float)(gd[i] / s);
    }

    int n_img = 2 * DIN * DIN * DIN;  // 14,155,776

    hipMemsetAsync(sum, 0, 8, stream);                 // replaces k_init
    k_minmax<<<MMB, 256, 0, stream>>>((const float4*)img1, n_img / 4, pbmx, pbmn);
    k_ssim<<<NBLK, 512, 0, stream>>>(img1, img2, pbmx, pbmn, sum, g);
    k_final<<<1, 1, 0, stream>>>(sum, out);
}